// Round 1
// baseline (78.090 us; speedup 1.0000x reference)
//
#include <hip/hip_runtime.h>
#include <hip/hip_bf16.h>

// softConLoss: loss = -mean_{i>=10} log_softmax_c( log(s_c(i)/py_c(i)) )[cls_i]
//   s_c(i) = sum_{j != i, cls_j == c} exp(feat_i . feat_j / 0.1)
// Strategy: bf16 MFMA Gram tiles; columns permuted+padded so each 32-col tile
// is single-class; exp2 with pre-scaled operand; exact pad/diagonal correction.

constexpr int NROWS = 8192;
constexpr int DIM   = 128;
constexpr int NCLS  = 10;
constexpr int CS    = 16;      // column splits (grid.y)
constexpr int MMAX  = 8512;    // >= 8192 + 10*31, padded perm rows cap
constexpr float SCALEF = 14.4269504089f; // (1/TEMP) * log2(e) = 10/ln(2)

typedef __attribute__((ext_vector_type(8)))  short  short8;
typedef __attribute__((ext_vector_type(16))) float  f32x16;

struct Meta { int cnt[NCLS]; int segStart[NCLS+1]; int padc[NCLS]; int M; int nTiles; };

// ---- workspace layout (bytes), total ~9.2 MB ----
constexpr size_t OFF_FEATB   = 0;                                  // bf16 [NROWS][DIM], scaled by SCALEF
constexpr size_t OFF_FEATA   = OFF_FEATB + (size_t)NROWS * DIM * 2; // bf16 [MMAX][DIM], permuted, unscaled
constexpr size_t OFF_SLAB    = OFF_FEATA + (size_t)MMAX * DIM * 2;  // f32 [CS][NROWS][NCLS]
constexpr size_t OFF_CLS     = OFF_SLAB + (size_t)CS * NROWS * NCLS * 4;
constexpr size_t OFF_PERM    = OFF_CLS + (size_t)NROWS * 4;
constexpr size_t OFF_TILECLS = OFF_PERM + (size_t)MMAX * 4;
constexpr size_t OFF_META    = OFF_TILECLS + 4 * 512;
constexpr size_t OFF_PART    = OFF_META + 256;

__device__ inline float exp2a(float x) {
#if __has_builtin(__builtin_amdgcn_exp2f)
  return __builtin_amdgcn_exp2f(x);
#else
  return exp2f(x);
#endif
}

// ---------- kernel 1: class ids, counts, padded permutation, tile classes ----------
__global__ void k_prep(const float* __restrict__ label, int* __restrict__ cls,
                       int* __restrict__ perm, int* __restrict__ tileCls,
                       Meta* __restrict__ meta) {
  __shared__ int scnt[NCLS];
  __shared__ int ssb[NCLS + 1];
  __shared__ int hist[256][NCLS];
  __shared__ int sM;
  const int tid = threadIdx.x;
  if (tid < NCLS) scnt[tid] = 0;
  __syncthreads();
  for (int i = tid; i < NROWS; i += 256) {
    int c = 0;
#pragma unroll
    for (int j = 0; j < NCLS; ++j) if (label[i * NCLS + j] > 0.5f) c = j;
    cls[i] = c;
    atomicAdd(&scnt[c], 1);
  }
  for (int p = tid; p < MMAX; p += 256) perm[p] = -1;
  __syncthreads();
  if (tid == 0) {
    int s = 0;
    for (int c = 0; c < NCLS; ++c) {
      ssb[c] = s;
      meta->cnt[c] = scnt[c];
      int seg = ((scnt[c] + 31) >> 5) << 5;
      meta->padc[c] = seg - scnt[c];
      s += seg;
    }
    ssb[NCLS] = s;
    meta->M = s;
    meta->nTiles = s >> 5;
    sM = s;
    for (int c = 0; c <= NCLS; ++c) meta->segStart[c] = ssb[c];
  }
  __syncthreads();
  // chunked (deterministic) grouping: 256 chunks x 32 rows
  for (int c = 0; c < NCLS; ++c) hist[tid][c] = 0;
  const int base = tid * 32;
  for (int r = 0; r < 32; ++r) hist[tid][cls[base + r]]++;
  __syncthreads();
  if (tid < NCLS) {           // serial exclusive prefix per class across chunks
    int run = 0;
    for (int t = 0; t < 256; ++t) { int v = hist[t][tid]; hist[t][tid] = run; run += v; }
  }
  __syncthreads();
  for (int r = 0; r < 32; ++r) {
    int i = base + r;
    int c = cls[i];
    int pos = ssb[c] + hist[tid][c];
    hist[tid][c] += 1;
    perm[pos] = i;
  }
  const int nT = sM >> 5;
  for (int t = tid; t < nT; t += 256) {
    int tc = 0;
    for (int c = 0; c < NCLS; ++c) if (ssb[c] <= t * 32) tc = c;
    tileCls[t] = tc;
  }
}

// ---------- kernel 2a: featB = bf16(feat * SCALEF) ----------
__global__ void k_convB(const float* __restrict__ feat, __hip_bfloat16* __restrict__ featB) {
  int e = (blockIdx.x * 256 + threadIdx.x) * 4;
  float4 v = *(const float4*)(feat + e);
  featB[e + 0] = __float2bfloat16(v.x * SCALEF);
  featB[e + 1] = __float2bfloat16(v.y * SCALEF);
  featB[e + 2] = __float2bfloat16(v.z * SCALEF);
  featB[e + 3] = __float2bfloat16(v.w * SCALEF);
}

// ---------- kernel 2b: featA = bf16(feat[perm]) (zeros for pads) ----------
__global__ void k_convA(const float* __restrict__ feat, const int* __restrict__ perm,
                        __hip_bfloat16* __restrict__ featA) {
  int e = (blockIdx.x * 256 + threadIdx.x) * 4;
  int p = e >> 7, k = e & 127;
  int src = perm[p];
  float4 v = make_float4(0.f, 0.f, 0.f, 0.f);
  if (src >= 0) v = *(const float4*)(feat + (size_t)src * DIM + k);
  featA[e + 0] = __float2bfloat16(v.x);
  featA[e + 1] = __float2bfloat16(v.y);
  featA[e + 2] = __float2bfloat16(v.z);
  featA[e + 3] = __float2bfloat16(v.w);
}

// ---------- kernel 3: main — Gram tiles -> exp2 -> per-class sums ----------
// block: 256 thr = 4 waves, each wave owns 32 rows (block owns 128 rows).
// grid: (64 row-blocks, CS column splits). A-tile (32 cols x 128 k) staged in LDS.
__global__ __launch_bounds__(256) void k_main(const __hip_bfloat16* __restrict__ featA,
                                              const __hip_bfloat16* __restrict__ featB,
                                              const int* __restrict__ tileCls,
                                              const Meta* __restrict__ meta,
                                              float* __restrict__ slab) {
  __shared__ __align__(16) char ldsA[32 * 256];  // 32 rows x 256 B, XOR-swizzled
  const int tid  = threadIdx.x;
  const int lane = tid & 63, wid = tid >> 6;
  const int il   = lane & 31, hi = lane >> 5;
  const int i    = blockIdx.x * 128 + wid * 32 + il;  // this lane's output row
  const int split = blockIdx.y;

  // B fragments: full half-row of featB[i] for this lane's k-half (32 VGPRs)
  const short8* fb = (const short8*)(featB + (size_t)i * DIM);
  short8 bfrag[8];
#pragma unroll
  for (int kk = 0; kk < 8; ++kk) bfrag[kk] = fb[kk * 2 + hi];

  float acc[NCLS];
#pragma unroll
  for (int c = 0; c < NCLS; ++c) acc[c] = 0.f;

  const int nT = meta->nTiles;
  for (int t = split; t < nT; t += CS) {
    // stage A tile (8 KB) coalesced, swizzled: byte col ^= (row&15)<<4
    const short8* srcA = (const short8*)(featA + (size_t)t * 32 * DIM);
#pragma unroll
    for (int it = 0; it < 2; ++it) {
      int slot = tid + it * 256;          // 512 slots = 32 rows x 16 segs
      int r = slot >> 4, s = slot & 15;
      int off = r * 256 + ((s * 16) ^ ((r & 15) << 4));
      *(short8*)(ldsA + off) = srcA[r * 16 + s];
    }
    __syncthreads();

    f32x16 Dv;
#pragma unroll
    for (int r = 0; r < 16; ++r) Dv[r] = 0.f;
#pragma unroll
    for (int kk = 0; kk < 8; ++kk) {
      int off = il * 256 + (((kk * 32) + hi * 16) ^ ((il & 15) << 4));
      short8 a = *(const short8*)(ldsA + off);
      Dv = __builtin_amdgcn_mfma_f32_32x32x16_bf16(a, bfrag[kk], Dv, 0, 0, 0);
    }

    float ts = 0.f;
#pragma unroll
    for (int r = 0; r < 16; ++r) ts += exp2a(Dv[r]);

    const int ct = tileCls[t];  // wave-uniform -> scalar branch, keeps acc in regs
    switch (ct) {
      case 0: acc[0] += ts; break;  case 1: acc[1] += ts; break;
      case 2: acc[2] += ts; break;  case 3: acc[3] += ts; break;
      case 4: acc[4] += ts; break;  case 5: acc[5] += ts; break;
      case 6: acc[6] += ts; break;  case 7: acc[7] += ts; break;
      case 8: acc[8] += ts; break;  default: acc[9] += ts; break;
    }
    __syncthreads();
  }

  // combine the two k-half lanes (same i)
#pragma unroll
  for (int c = 0; c < NCLS; ++c) acc[c] += __shfl_xor(acc[c], 32, 64);
  if (lane < 32) {
    float* dst = slab + ((size_t)split * NROWS + i) * NCLS;
#pragma unroll
    for (int c = 0; c < NCLS; ++c) dst[c] = acc[c];
  }
}

// ---------- kernel 4: per-row loss + block partial sums ----------
__global__ void k_fin(const float* __restrict__ feat, const int* __restrict__ cls,
                      const float* __restrict__ slab, const Meta* __restrict__ meta,
                      float* __restrict__ partials) {
  __shared__ float red[256];
  const int tid = threadIdx.x;
  const int i = blockIdx.x * 256 + tid;
  const int ci = cls[i];
  float s[NCLS];
#pragma unroll
  for (int c = 0; c < NCLS; ++c) s[c] = 0.f;
#pragma unroll
  for (int sp = 0; sp < CS; ++sp) {
    const float* p = slab + ((size_t)sp * NROWS + i) * NCLS;
#pragma unroll
    for (int c = 0; c < NCLS; ++c) s[c] += p[c];
  }
  // exact pad correction: each pad row contributed exp2(0)=1 to its class
#pragma unroll
  for (int c = 0; c < NCLS; ++c) s[c] -= (float)meta->padc[c];
  // diagonal: recompute with identical bf16 roundings (only sum order differs)
  float sd = 0.f;
  const float* fr = feat + (size_t)i * DIM;
#pragma unroll 8
  for (int k = 0; k < DIM; ++k) {
    float a = __bfloat162float(__float2bfloat16(fr[k]));
    float b = __bfloat162float(__float2bfloat16(fr[k] * SCALEF));
    sd += a * b;
  }
  const float self = exp2a(sd);
  float L[NCLS];
  float mx = -1e30f;
#pragma unroll
  for (int c = 0; c < NCLS; ++c) {
    float sc = s[c] - ((c == ci) ? self : 0.f);
    float py = (float)meta->cnt[c] - ((c == ci) ? 1.f : 0.f);
    L[c] = __logf(sc) - __logf(py);
    mx = fmaxf(mx, L[c]);
  }
  float sum = 0.f, Lt = 0.f;
#pragma unroll
  for (int c = 0; c < NCLS; ++c) {
    sum += __expf(L[c] - mx);
    Lt += (c == ci) ? L[c] : 0.f;
  }
  const float lse = mx + __logf(sum);
  red[tid] = (i >= NCLS) ? (lse - Lt) : 0.f;
  __syncthreads();
  for (int st = 128; st > 0; st >>= 1) {
    if (tid < st) red[tid] += red[tid + st];
    __syncthreads();
  }
  if (tid == 0) partials[blockIdx.x] = red[0];
}

// ---------- kernel 5: final scalar ----------
__global__ void k_red(const float* __restrict__ partials, float* __restrict__ out) {
  if (threadIdx.x == 0) {
    float s = 0.f;
    for (int b = 0; b < 32; ++b) s += partials[b];
    out[0] = s / (float)(NROWS - NCLS);
  }
}

extern "C" void kernel_launch(void* const* d_in, const int* in_sizes, int n_in,
                              void* d_out, int out_size, void* d_ws, size_t ws_size,
                              hipStream_t stream) {
  const float* label = (const float*)d_in[0];
  const float* feat  = (const float*)d_in[1];
  char* w = (char*)d_ws;
  __hip_bfloat16* featB = (__hip_bfloat16*)(w + OFF_FEATB);
  __hip_bfloat16* featA = (__hip_bfloat16*)(w + OFF_FEATA);
  float* slab   = (float*)(w + OFF_SLAB);
  int*   cls    = (int*)(w + OFF_CLS);
  int*   perm   = (int*)(w + OFF_PERM);
  int*   tileCls= (int*)(w + OFF_TILECLS);
  Meta*  meta   = (Meta*)(w + OFF_META);
  float* part   = (float*)(w + OFF_PART);

  k_prep<<<1, 256, 0, stream>>>(label, cls, perm, tileCls, meta);
  k_convB<<<(NROWS * DIM) / 1024, 256, 0, stream>>>(feat, featB);
  k_convA<<<(MMAX * DIM) / 1024, 256, 0, stream>>>(feat, perm, featA);
  k_main<<<dim3(64, CS), 256, 0, stream>>>(featA, featB, tileCls, meta, slab);
  k_fin<<<NROWS / 256, 256, 0, stream>>>(feat, cls, slab, meta, part);
  k_red<<<1, 64, 0, stream>>>(part, (float*)d_out);
}